// Round 11
// baseline (831.174 us; speedup 1.0000x reference)
//
#include <hip/hip_runtime.h>

// RWKV-7 Tmix (B=4, T=1024, C=1024, H=16, HS=64, H_KV=4)
// Round 10: R9's wave-private global_load_lds depth-4 pipeline with the
// vmcnt STORE-COUNTING FIX: y-stores also increment vmcnt, so the steady
// wait is vmcnt(21) = 18 loads (3 groups) + 3 in-window stores; iterations
// 0..2 peeled at vmcnt(18/19/20). R9's vmcnt(18) over-waited into group
// t+2 and exposed L2 latency every step.

#define NROWS 4096      // B*T
#define CCH   1024
#define EPSV  0.00064f

typedef __attribute__((ext_vector_type(4))) float f32x4;
typedef __attribute__((ext_vector_type(8))) short bf16x8;

__device__ __forceinline__ unsigned short f2b(float f) {
    unsigned x = __float_as_uint(f);
    return (unsigned short)((x + 0x7fffu + ((x >> 16) & 1u)) >> 16);
}
__device__ __forceinline__ float b2f(unsigned short u) {
    return __uint_as_float(((unsigned)u) << 16);
}

#define LDSTR 40

// ---------------------------------------------------------------------------
// Split-precision MFMA GEMM: C[M,N] = A[M,K]*B[N,K]^T (f32 in/out).
// ---------------------------------------------------------------------------
template<bool TANH>
__global__ __launch_bounds__(256) void gemm_split(
    const float* __restrict__ A, int lda, const float* __restrict__ B, int ldb,
    float* __restrict__ C, int ldc, int M, int N, int K, int tl, int th)
{
    __shared__ __align__(16) unsigned short Ah[128 * LDSTR];
    __shared__ __align__(16) unsigned short Al[128 * LDSTR];
    __shared__ __align__(16) unsigned short Bh[128 * LDSTR];
    __shared__ __align__(16) unsigned short Bl[128 * LDSTR];
    const int t = threadIdx.x;
    const int wave = t >> 6, lane = t & 63;
    const int m0 = blockIdx.y * 128, n0 = blockIdx.x * 128;
    const int wm = (wave >> 1) * 64, wn = (wave & 1) * 64;
    const int fr = lane & 15, kq = lane >> 4;

    f32x4 acc[4][4];
    #pragma unroll
    for (int i = 0; i < 4; ++i)
        #pragma unroll
        for (int j = 0; j < 4; ++j)
            acc[i][j] = (f32x4){0.f, 0.f, 0.f, 0.f};

    const int srow = t >> 3;         // 0..31
    const int scol = (t & 7) * 4;    // 0,4,..,28

    for (int k0 = 0; k0 < K; k0 += 32) {
        #pragma unroll
        for (int p = 0; p < 4; ++p) {
            const int row = p * 32 + srow;
            {
                const float4 v = *reinterpret_cast<const float4*>(
                    A + (size_t)(m0 + row) * lda + k0 + scol);
                ushort4 h, l;
                h.x = f2b(v.x); l.x = f2b(v.x - b2f(h.x));
                h.y = f2b(v.y); l.y = f2b(v.y - b2f(h.y));
                h.z = f2b(v.z); l.z = f2b(v.z - b2f(h.z));
                h.w = f2b(v.w); l.w = f2b(v.w - b2f(h.w));
                *reinterpret_cast<ushort4*>(&Ah[row * LDSTR + scol]) = h;
                *reinterpret_cast<ushort4*>(&Al[row * LDSTR + scol]) = l;
            }
            {
                float4 v = make_float4(0.f, 0.f, 0.f, 0.f);
                if (n0 + row < N)
                    v = *reinterpret_cast<const float4*>(
                        B + (size_t)(n0 + row) * ldb + k0 + scol);
                ushort4 h, l;
                h.x = f2b(v.x); l.x = f2b(v.x - b2f(h.x));
                h.y = f2b(v.y); l.y = f2b(v.y - b2f(h.y));
                h.z = f2b(v.z); l.z = f2b(v.z - b2f(h.z));
                h.w = f2b(v.w); l.w = f2b(v.w - b2f(h.w));
                *reinterpret_cast<ushort4*>(&Bh[row * LDSTR + scol]) = h;
                *reinterpret_cast<ushort4*>(&Bl[row * LDSTR + scol]) = l;
            }
        }
        __syncthreads();

        bf16x8 ah[4], al[4], bh[4], bl[4];
        #pragma unroll
        for (int mi = 0; mi < 4; ++mi) {
            ah[mi] = *reinterpret_cast<const bf16x8*>(&Ah[(wm + mi * 16 + fr) * LDSTR + kq * 8]);
            al[mi] = *reinterpret_cast<const bf16x8*>(&Al[(wm + mi * 16 + fr) * LDSTR + kq * 8]);
        }
        #pragma unroll
        for (int ni = 0; ni < 4; ++ni) {
            bh[ni] = *reinterpret_cast<const bf16x8*>(&Bh[(wn + ni * 16 + fr) * LDSTR + kq * 8]);
            bl[ni] = *reinterpret_cast<const bf16x8*>(&Bl[(wn + ni * 16 + fr) * LDSTR + kq * 8]);
        }
        #pragma unroll
        for (int mi = 0; mi < 4; ++mi)
            #pragma unroll
            for (int ni = 0; ni < 4; ++ni) {
                acc[mi][ni] = __builtin_amdgcn_mfma_f32_16x16x32_bf16(
                    al[mi], bh[ni], acc[mi][ni], 0, 0, 0);
                acc[mi][ni] = __builtin_amdgcn_mfma_f32_16x16x32_bf16(
                    ah[mi], bl[ni], acc[mi][ni], 0, 0, 0);
                acc[mi][ni] = __builtin_amdgcn_mfma_f32_16x16x32_bf16(
                    ah[mi], bh[ni], acc[mi][ni], 0, 0, 0);
            }
        __syncthreads();
    }

    const int crow0 = m0 + wm + kq * 4;
    const int ccol0 = n0 + wn + fr;
    #pragma unroll
    for (int mi = 0; mi < 4; ++mi)
        #pragma unroll
        for (int ni = 0; ni < 4; ++ni) {
            const int col = ccol0 + ni * 16;
            if (col < N) {
                #pragma unroll
                for (int i = 0; i < 4; ++i) {
                    float v = acc[mi][ni][i];
                    if (TANH && col >= tl && col < th) v = tanhf(v);
                    C[(size_t)(crow0 + mi * 16 + i) * ldc + col] = v;
                }
            }
        }
}

// ---------------------------------------------------------------------------
// Plain bf16 MFMA GEMM (output projection — no error amplification).
// ---------------------------------------------------------------------------
__global__ __launch_bounds__(256) void gemm_mfma(
    const float* __restrict__ A, const float* __restrict__ B,
    float* __restrict__ C, int M, int N, int K)
{
    __shared__ __align__(16) unsigned short Ah[128 * LDSTR];
    __shared__ __align__(16) unsigned short Bh[128 * LDSTR];
    const int t = threadIdx.x;
    const int wave = t >> 6, lane = t & 63;
    const int m0 = blockIdx.y * 128, n0 = blockIdx.x * 128;
    const int wm = (wave >> 1) * 64, wn = (wave & 1) * 64;
    const int fr = lane & 15, kq = lane >> 4;

    f32x4 acc[4][4];
    #pragma unroll
    for (int i = 0; i < 4; ++i)
        #pragma unroll
        for (int j = 0; j < 4; ++j)
            acc[i][j] = (f32x4){0.f, 0.f, 0.f, 0.f};

    const int srow = t >> 3;
    const int scol = (t & 7) * 4;

    for (int k0 = 0; k0 < 1024; k0 += 32) {
        #pragma unroll
        for (int p = 0; p < 4; ++p) {
            const int row = p * 32 + srow;
            const float4 av = *reinterpret_cast<const float4*>(
                A + (size_t)(m0 + row) * 1024 + k0 + scol);
            ushort4 a4;
            a4.x = f2b(av.x); a4.y = f2b(av.y); a4.z = f2b(av.z); a4.w = f2b(av.w);
            *reinterpret_cast<ushort4*>(&Ah[row * LDSTR + scol]) = a4;
            const float4 bv = *reinterpret_cast<const float4*>(
                B + (size_t)(n0 + row) * 1024 + k0 + scol);
            ushort4 b4;
            b4.x = f2b(bv.x); b4.y = f2b(bv.y); b4.z = f2b(bv.z); b4.w = f2b(bv.w);
            *reinterpret_cast<ushort4*>(&Bh[row * LDSTR + scol]) = b4;
        }
        __syncthreads();

        bf16x8 af[4], bfr[4];
        #pragma unroll
        for (int mi = 0; mi < 4; ++mi)
            af[mi] = *reinterpret_cast<const bf16x8*>(&Ah[(wm + mi * 16 + fr) * LDSTR + kq * 8]);
        #pragma unroll
        for (int ni = 0; ni < 4; ++ni)
            bfr[ni] = *reinterpret_cast<const bf16x8*>(&Bh[(wn + ni * 16 + fr) * LDSTR + kq * 8]);
        #pragma unroll
        for (int mi = 0; mi < 4; ++mi)
            #pragma unroll
            for (int ni = 0; ni < 4; ++ni)
                acc[mi][ni] = __builtin_amdgcn_mfma_f32_16x16x32_bf16(
                    af[mi], bfr[ni], acc[mi][ni], 0, 0, 0);
        __syncthreads();
    }

    const int crow0 = m0 + wm + kq * 4;
    const int ccol0 = n0 + wn + fr;
    #pragma unroll
    for (int mi = 0; mi < 4; ++mi)
        #pragma unroll
        for (int ni = 0; ni < 4; ++ni) {
            const int col = ccol0 + ni * 16;
            #pragma unroll
            for (int i = 0; i < 4; ++i)
                C[(size_t)(crow0 + mi * 16 + i) * 1024 + col] = acc[mi][ni][i];
        }
}

// ---------------------------------------------------------------------------
// Weight packing: Wkvh[672][1024] = [Wk; Wv; w1^T; a1^T; v1^T];
// w2T[1024][64], a2T[1024][64], v2T[1024][32] transposes.
// ---------------------------------------------------------------------------
__global__ __launch_bounds__(256) void pack_all(
    const float* __restrict__ Wk, const float* __restrict__ Wv,
    const float* __restrict__ w1, const float* __restrict__ a1,
    const float* __restrict__ v1, const float* __restrict__ w2,
    const float* __restrict__ a2, const float* __restrict__ v2,
    float* __restrict__ Wkvh,
    float* __restrict__ w2T, float* __restrict__ a2T, float* __restrict__ v2T)
{
    const int blk = blockIdx.x, t = threadIdx.x;
    if (blk < 512) {
        const float* s = blk < 256 ? Wk + (size_t)blk * 1024
                                   : Wv + (size_t)(blk - 256) * 1024;
        const float4 v = *reinterpret_cast<const float4*>(s + t * 4);
        *reinterpret_cast<float4*>(Wkvh + (size_t)blk * 1024 + t * 4) = v;
    } else if (blk < 672) {
        const int f = blk - 512;     // 0..159
        for (int c = t; c < 1024; c += 256) {
            float val;
            if (f < 64)       val = w1[c * 64 + f];
            else if (f < 128) val = a1[c * 64 + (f - 64)];
            else              val = v1[c * 32 + (f - 128)];
            Wkvh[(size_t)(512 + f) * 1024 + c] = val;
        }
    } else {
        const int c = blk - 672;     // 0..1023
        if (t < 64)       w2T[c * 64 + t]         = w2[t * 1024 + c];
        else if (t < 128) a2T[c * 64 + (t - 64)]  = a2[(t - 64) * 1024 + c];
        else if (t < 160) v2T[c * 32 + (t - 128)] = v2[(t - 128) * 1024 + c];
    }
}

// ---------------------------------------------------------------------------
// Slim fuse_pre: dd/aacc/vacc precomputed (GEMM) in buffers that ALIAS
// wdec/kf/vf (read idx then write idx — safe). kvh row stride 672.
// ---------------------------------------------------------------------------
__global__ __launch_bounds__(256) void fuse_pre(
    const float* __restrict__ kvh,
    const float* __restrict__ v_first, const float* __restrict__ mask,
    const float* __restrict__ w0, const float* __restrict__ a0,
    const float* __restrict__ v0,
    const float* __restrict__ k_k, const float* __restrict__ k_a,
    float* __restrict__ wdec, float* __restrict__ kf, float* __restrict__ vf,
    float* __restrict__ aab, float* __restrict__ bbb)
{
    const int n = blockIdx.x, t = threadIdx.x;
    const float m = mask[n];
    const bool live = m > 0.f;

    #pragma unroll
    for (int q = 0; q < 4; ++q) {
        const int c = q * 256 + t;
        const size_t idx = (size_t)n * 1024 + c;
        const float dd   = w0[c] + wdec[idx];   // ddl
        const float aacc = a0[c] + kf[idx];     // aal
        const float vacc = v0[c] + vf[idx];     // vvl

        const float u  = -dd;
        const float sp = fmaxf(u, 0.f) + log1pf(expf(-fabsf(u)));
        const float dec = expf(-expf(-sp - 0.6f));
        const float av = 1.f / (1.f + expf(-aacc));
        const float sv = 1.f / (1.f + expf(-vacc));

        const int  ck  = q * 64 + (c & 63);
        const float kr = kvh[(size_t)n * 672 + ck];
        const float vr = kvh[(size_t)n * 672 + 256 + ck];
        const float vfi = v_first[idx];
        const float vv  = vr + (vfi - vr) * sv;

        const float tkk = kr * k_k[c];
        float ss = tkk * tkk;
        #pragma unroll
        for (int off = 32; off > 0; off >>= 1) ss += __shfl_xor(ss, off, 64);
        const float kkv = tkk / fmaxf(sqrtf(ss), 1e-12f);

        wdec[idx] = live ? dec : 1.f;
        kf[idx]   = kr * (1.f + (av - 1.f) * k_a[c]) * m;
        vf[idx]   = vv * m;
        aab[idx]  = -kkv * m;
        bbb[idx]  = kkv * av * m;
    }
}

// ---------------------------------------------------------------------------
// WKV7: 256 blocks x 4 waves; wave = (bh, 4 value-rows), 16 lanes/row,
// float4 channels, DPP-only reduces. Wave-private global_load_lds depth-4
// pipeline, NO barriers. vmcnt accounts for y-stores: steady wait = 21
// (18 loads + 3 stores in window); iters 0..2 peeled at 18/19/20.
// ---------------------------------------------------------------------------
__device__ __forceinline__ float qred16(float x) {
    x += __int_as_float(__builtin_amdgcn_update_dpp(
        0, __float_as_int(x), 0xB1, 0xF, 0xF, true));   // quad_perm xor1
    x += __int_as_float(__builtin_amdgcn_update_dpp(
        0, __float_as_int(x), 0x4E, 0xF, 0xF, true));   // quad_perm xor2
    x += __int_as_float(__builtin_amdgcn_update_dpp(
        0, __float_as_int(x), 0x141, 0xF, 0xF, true));  // row_half_mirror
    x += __int_as_float(__builtin_amdgcn_update_dpp(
        0, __float_as_int(x), 0x140, 0xF, 0xF, true));  // row_mirror
    return x;
}

__global__ __launch_bounds__(256, 1) void wkv7(
    const float* __restrict__ r, const float* __restrict__ wdec,
    const float* __restrict__ kf, const float* __restrict__ vf,
    const float* __restrict__ aab, const float* __restrict__ bbb,
    float* __restrict__ y)
{
    __shared__ __align__(16) float slb[4][5][6][64];
    const int blk = blockIdx.x;               // 0..255
    const int m  = blk & 7;
    const int s  = blk >> 3;                  // 0..31
    const int bh = (s >> 2) * 8 + m;          // 4 blocks of bh share m -> same XCD
    const int j  = s & 3;
    const int b = bh >> 4, h = bh & 15;
    const int wave = threadIdx.x >> 6;
    const int lane = threadIdx.x & 63;
    const int li   = lane & 15;
    const int i    = j * 16 + wave * 4 + (lane >> 4);  // value row 0..63
    const int c0   = li * 4;
    const size_t cb = (size_t)b * (1024 * 1024) + (size_t)h * 64;

    float (*sl)[6][64] = slb[wave];   // wave-private region

#define GLLW(g, l) __builtin_amdgcn_global_load_lds( \
        (const __attribute__((address_space(1))) unsigned int*)(g), \
        (__attribute__((address_space(3))) unsigned int*)(l), 4, 0, 0)

#define ISSUE(T, SLOT) { \
        const size_t p_ = cb + (size_t)(T) * 1024 + lane; \
        GLLW(wdec + p_, &sl[SLOT][0][0]); \
        GLLW(kf   + p_, &sl[SLOT][1][0]); \
        GLLW(aab  + p_, &sl[SLOT][2][0]); \
        GLLW(bbb  + p_, &sl[SLOT][3][0]); \
        GLLW(r    + p_, &sl[SLOT][4][0]); \
        GLLW(vf   + p_, &sl[SLOT][5][0]); }

#define ITER(T, WSTR) { \
        const int wslot_ = ((T) + 4) % 5; \
        const int nslot_ = ((T) + 1) % 5; \
        const int tt_ = (T) + 4 < 1024 ? (T) + 4 : 1023; \
        ISSUE(tt_, wslot_); \
        asm volatile(WSTR ::: "memory"); \
        __builtin_amdgcn_sched_barrier(0); \
        const float4 dN = *reinterpret_cast<const float4*>(&sl[nslot_][0][c0]); \
        const float4 kN = *reinterpret_cast<const float4*>(&sl[nslot_][1][c0]); \
        const float4 aN = *reinterpret_cast<const float4*>(&sl[nslot_][2][c0]); \
        const float4 bN = *reinterpret_cast<const float4*>(&sl[nslot_][3][c0]); \
        const float4 rN = *reinterpret_cast<const float4*>(&sl[nslot_][4][c0]); \
        const float  vN = sl[nslot_][5][i]; \
        float sa = S.x * aC.x + S.y * aC.y + S.z * aC.z + S.w * aC.w; \
        sa = qred16(sa); \
        S.x = S.x * dC.x + sa * bC.x + vC * kC.x; \
        S.y = S.y * dC.y + sa * bC.y + vC * kC.y; \
        S.z = S.z * dC.z + sa * bC.z + vC * kC.z; \
        S.w = S.w * dC.w + sa * bC.w + vC * kC.w; \
        float yv = S.x * rC.x + S.y * rC.y + S.z * rC.z + S.w * rC.w; \
        yv = qred16(yv); \
        if (li == 0) y[cb + (size_t)(T) * 1024 + i] = yv; \
        dC = dN; kC = kN; aC = aN; bC = bN; rC = rN; vC = vN; }

    // prologue: stage slots 0..3 (groups g0..g3, 24 loads)
    ISSUE(0, 0); ISSUE(1, 1); ISSUE(2, 2); ISSUE(3, 3);
    asm volatile("s_waitcnt vmcnt(18)" ::: "memory");   // g0 retired
    __builtin_amdgcn_sched_barrier(0);

    // preload slot 0 into current regs
    float4 dC = *reinterpret_cast<const float4*>(&sl[0][0][c0]);
    float4 kC = *reinterpret_cast<const float4*>(&sl[0][1][c0]);
    float4 aC = *reinterpret_cast<const float4*>(&sl[0][2][c0]);
    float4 bC = *reinterpret_cast<const float4*>(&sl[0][3][c0]);
    float4 rC = *reinterpret_cast<const float4*>(&sl[0][4][c0]);
    float  vC = sl[0][5][i];

    float4 S = make_float4(0.f, 0.f, 0.f, 0.f);

    // peeled iterations: store count in the vmcnt window ramps 0 -> 3
    ITER(0, "s_waitcnt vmcnt(18)");
    ITER(1, "s_waitcnt vmcnt(19)");
    ITER(2, "s_waitcnt vmcnt(20)");
    for (int t = 3; t < 1024; ++t) {
        ITER(t, "s_waitcnt vmcnt(21)");
    }
#undef ITER
#undef ISSUE
#undef GLLW
}

// ---------------------------------------------------------------------------
// Post: groupnorm per (row, head) + rk*v residual
// ---------------------------------------------------------------------------
__global__ __launch_bounds__(256) void fuse_post(
    const float* __restrict__ y, const float* __restrict__ r,
    const float* __restrict__ kf, const float* __restrict__ vf,
    const float* __restrict__ r_k, const float* __restrict__ ln_g, const float* __restrict__ ln_b,
    float* __restrict__ yn)
{
    const int n = blockIdx.x, t = threadIdx.x;
    #pragma unroll
    for (int q = 0; q < 4; ++q) {
        const int c = q * 256 + t;
        const size_t idx = (size_t)n * 1024 + c;
        const float yv = y[idx];
        float s1 = yv, s2 = yv * yv;
        float rk = r[idx] * kf[idx] * r_k[c];
        #pragma unroll
        for (int off = 32; off > 0; off >>= 1) {
            s1 += __shfl_xor(s1, off, 64);
            s2 += __shfl_xor(s2, off, 64);
            rk += __shfl_xor(rk, off, 64);
        }
        const float mu  = s1 * (1.f / 64.f);
        const float var = s2 * (1.f / 64.f) - mu * mu;
        yn[idx] = (yv - mu) * rsqrtf(var + EPSV) * ln_g[c] + ln_b[c]
                  + rk * vf[idx];
    }
}

// ---------------------------------------------------------------------------
extern "C" void kernel_launch(void* const* d_in, const int* in_sizes, int n_in,
                              void* d_out, int out_size, void* d_ws, size_t ws_size,
                              hipStream_t stream)
{
    const float* x       = (const float*)d_in[0];
    const float* v_first = (const float*)d_in[1];
    const float* mask    = (const float*)d_in[2];
    const float* Wr      = (const float*)d_in[3];
    const float* Wk      = (const float*)d_in[4];
    const float* Wv      = (const float*)d_in[5];
    const float* Wo      = (const float*)d_in[6];
    const float* w0      = (const float*)d_in[7];
    const float* w1      = (const float*)d_in[8];
    const float* w2      = (const float*)d_in[9];
    const float* a0      = (const float*)d_in[10];
    const float* a1      = (const float*)d_in[11];
    const float* a2      = (const float*)d_in[12];
    const float* v0      = (const float*)d_in[13];
    const float* v1      = (const float*)d_in[14];
    const float* v2      = (const float*)d_in[15];
    const float* k_k     = (const float*)d_in[16];
    const float* k_a     = (const float*)d_in[17];
    const float* r_k     = (const float*)d_in[18];
    const float* ln_g    = (const float*)d_in[19];
    const float* ln_b    = (const float*)d_in[20];
    float* out = (float*)d_out;

    float* ws = (float*)d_ws;
    const size_t M4 = (size_t)NROWS * CCH;   // 4M elements
    float* rbuf = ws;
    float* wdec = ws + 1 * M4;   // pre-fuse_pre: ddl
    float* kf   = ws + 2 * M4;   // pre-fuse_pre: aal
    float* vf   = ws + 3 * M4;   // pre-fuse_pre: vvl
    float* aab  = ws + 4 * M4;   // post-wkv7: yn
    float* bbb  = ws + 5 * M4;
    float* ybuf = ws + 6 * M4;
    // region-6 temps (dead before wkv7 writes ybuf):
    float* kvh  = ybuf;                          // [4096][672]
    float* w2T  = kvh  + (size_t)NROWS * 672;    // [1024][64]
    float* a2T  = w2T  + (size_t)1024 * 64;      // [1024][64]
    float* v2T  = a2T  + (size_t)1024 * 64;      // [1024][32]
    float* Wkvh = v2T  + (size_t)1024 * 32;      // [672][1024]
    float* yn = aab;

    dim3 blk(256);
    pack_all<<<1696, blk, 0, stream>>>(Wk, Wv, w1, a1, v1, w2, a2, v2,
                                       Wkvh, w2T, a2T, v2T);
    gemm_split<false><<<dim3(8, 32), blk, 0, stream>>>(
        x, 1024, Wr, 1024, rbuf, 1024, NROWS, 1024, 1024, 0, 0);
    gemm_split<true><<<dim3(6, 32), blk, 0, stream>>>(
        x, 1024, Wkvh, 1024, kvh, 672, NROWS, 672, 1024, 512, 576);
    // stage-2: dd -> wdec(ddl), aa -> kf(aal), vv -> vf(vvl)
    gemm_split<false><<<dim3(8, 32), blk, 0, stream>>>(
        kvh + 512, 672, w2T, 64, wdec, 1024, NROWS, 1024, 64, 0, 0);
    gemm_split<false><<<dim3(8, 32), blk, 0, stream>>>(
        kvh + 576, 672, a2T, 64, kf, 1024, NROWS, 1024, 64, 0, 0);
    gemm_split<false><<<dim3(8, 32), blk, 0, stream>>>(
        kvh + 640, 672, v2T, 32, vf, 1024, NROWS, 1024, 32, 0, 0);
    fuse_pre<<<NROWS, blk, 0, stream>>>(kvh, v_first, mask, w0, a0, v0,
                                        k_k, k_a, wdec, kf, vf, aab, bbb);
    wkv7<<<256, blk, 0, stream>>>(rbuf, wdec, kf, vf, aab, bbb, ybuf);
    fuse_post<<<NROWS, blk, 0, stream>>>(ybuf, rbuf, kf, vf, r_k, ln_g, ln_b, yn);
    gemm_mfma<<<dim3(8, 32), blk, 0, stream>>>(yn, Wo, out, NROWS, 1024, 1024);
    hipMemcpyAsync(out + M4, v_first, M4 * sizeof(float),
                   hipMemcpyDeviceToDevice, stream);
}

// Round 12
// 550.551 us; speedup vs baseline: 1.5097x; 1.5097x over previous
//
#include <hip/hip_runtime.h>

// RWKV-7 Tmix (B=4, T=1024, C=1024, H=16, HS=64, H_KV=4)
// Round 11: wkv7 reverted to R8's proven version (294us). GEMM precision
// targeted: split-precision kept ONLY for kvh (k/v feed the recurrence);
// r-GEMM and the three stage-2 GEMMs (dd/aa/vv) downgraded to plain bf16
// MFMA (no recurrence amplification; error budget analysis in journal).

#define NROWS 4096      // B*T
#define CCH   1024
#define EPSV  0.00064f

typedef __attribute__((ext_vector_type(4))) float f32x4;
typedef __attribute__((ext_vector_type(8))) short bf16x8;

__device__ __forceinline__ unsigned short f2b(float f) {
    unsigned x = __float_as_uint(f);
    return (unsigned short)((x + 0x7fffu + ((x >> 16) & 1u)) >> 16);
}
__device__ __forceinline__ float b2f(unsigned short u) {
    return __uint_as_float(((unsigned)u) << 16);
}

#define LDSTR 40

// ---------------------------------------------------------------------------
// Split-precision MFMA GEMM: C[M,N] = A[M,K]*B[N,K]^T (f32 in/out).
// A,B -> bf16 hi+lo; C += Ahi*Bhi + Ahi*Blo + Alo*Bhi.
// BM=BN=128, BK=32, 256 thr = 4 waves. TANH: tanh() on cols in [tl,th).
// ---------------------------------------------------------------------------
template<bool TANH>
__global__ __launch_bounds__(256) void gemm_split(
    const float* __restrict__ A, int lda, const float* __restrict__ B, int ldb,
    float* __restrict__ C, int ldc, int M, int N, int K, int tl, int th)
{
    __shared__ __align__(16) unsigned short Ah[128 * LDSTR];
    __shared__ __align__(16) unsigned short Al[128 * LDSTR];
    __shared__ __align__(16) unsigned short Bh[128 * LDSTR];
    __shared__ __align__(16) unsigned short Bl[128 * LDSTR];
    const int t = threadIdx.x;
    const int wave = t >> 6, lane = t & 63;
    const int m0 = blockIdx.y * 128, n0 = blockIdx.x * 128;
    const int wm = (wave >> 1) * 64, wn = (wave & 1) * 64;
    const int fr = lane & 15, kq = lane >> 4;

    f32x4 acc[4][4];
    #pragma unroll
    for (int i = 0; i < 4; ++i)
        #pragma unroll
        for (int j = 0; j < 4; ++j)
            acc[i][j] = (f32x4){0.f, 0.f, 0.f, 0.f};

    const int srow = t >> 3;         // 0..31
    const int scol = (t & 7) * 4;    // 0,4,..,28

    for (int k0 = 0; k0 < K; k0 += 32) {
        #pragma unroll
        for (int p = 0; p < 4; ++p) {
            const int row = p * 32 + srow;
            {
                const float4 v = *reinterpret_cast<const float4*>(
                    A + (size_t)(m0 + row) * lda + k0 + scol);
                ushort4 h, l;
                h.x = f2b(v.x); l.x = f2b(v.x - b2f(h.x));
                h.y = f2b(v.y); l.y = f2b(v.y - b2f(h.y));
                h.z = f2b(v.z); l.z = f2b(v.z - b2f(h.z));
                h.w = f2b(v.w); l.w = f2b(v.w - b2f(h.w));
                *reinterpret_cast<ushort4*>(&Ah[row * LDSTR + scol]) = h;
                *reinterpret_cast<ushort4*>(&Al[row * LDSTR + scol]) = l;
            }
            {
                float4 v = make_float4(0.f, 0.f, 0.f, 0.f);
                if (n0 + row < N)
                    v = *reinterpret_cast<const float4*>(
                        B + (size_t)(n0 + row) * ldb + k0 + scol);
                ushort4 h, l;
                h.x = f2b(v.x); l.x = f2b(v.x - b2f(h.x));
                h.y = f2b(v.y); l.y = f2b(v.y - b2f(h.y));
                h.z = f2b(v.z); l.z = f2b(v.z - b2f(h.z));
                h.w = f2b(v.w); l.w = f2b(v.w - b2f(h.w));
                *reinterpret_cast<ushort4*>(&Bh[row * LDSTR + scol]) = h;
                *reinterpret_cast<ushort4*>(&Bl[row * LDSTR + scol]) = l;
            }
        }
        __syncthreads();

        bf16x8 ah[4], al[4], bh[4], bl[4];
        #pragma unroll
        for (int mi = 0; mi < 4; ++mi) {
            ah[mi] = *reinterpret_cast<const bf16x8*>(&Ah[(wm + mi * 16 + fr) * LDSTR + kq * 8]);
            al[mi] = *reinterpret_cast<const bf16x8*>(&Al[(wm + mi * 16 + fr) * LDSTR + kq * 8]);
        }
        #pragma unroll
        for (int ni = 0; ni < 4; ++ni) {
            bh[ni] = *reinterpret_cast<const bf16x8*>(&Bh[(wn + ni * 16 + fr) * LDSTR + kq * 8]);
            bl[ni] = *reinterpret_cast<const bf16x8*>(&Bl[(wn + ni * 16 + fr) * LDSTR + kq * 8]);
        }
        #pragma unroll
        for (int mi = 0; mi < 4; ++mi)
            #pragma unroll
            for (int ni = 0; ni < 4; ++ni) {
                acc[mi][ni] = __builtin_amdgcn_mfma_f32_16x16x32_bf16(
                    al[mi], bh[ni], acc[mi][ni], 0, 0, 0);
                acc[mi][ni] = __builtin_amdgcn_mfma_f32_16x16x32_bf16(
                    ah[mi], bl[ni], acc[mi][ni], 0, 0, 0);
                acc[mi][ni] = __builtin_amdgcn_mfma_f32_16x16x32_bf16(
                    ah[mi], bh[ni], acc[mi][ni], 0, 0, 0);
            }
        __syncthreads();
    }

    const int crow0 = m0 + wm + kq * 4;
    const int ccol0 = n0 + wn + fr;
    #pragma unroll
    for (int mi = 0; mi < 4; ++mi)
        #pragma unroll
        for (int ni = 0; ni < 4; ++ni) {
            const int col = ccol0 + ni * 16;
            if (col < N) {
                #pragma unroll
                for (int i = 0; i < 4; ++i) {
                    float v = acc[mi][ni][i];
                    if (TANH && col >= tl && col < th) v = tanhf(v);
                    C[(size_t)(crow0 + mi * 16 + i) * ldc + col] = v;
                }
            }
        }
}

// ---------------------------------------------------------------------------
// Plain bf16 MFMA GEMM, generalized dims (r-GEMM, stage-2, out-GEMM).
// N must be a multiple of 128; K a multiple of 32 (or 32 itself).
// ---------------------------------------------------------------------------
__global__ __launch_bounds__(256) void gemm_mfma(
    const float* __restrict__ A, int lda, const float* __restrict__ B, int ldb,
    float* __restrict__ C, int ldc, int M, int N, int K)
{
    __shared__ __align__(16) unsigned short Ah[128 * LDSTR];
    __shared__ __align__(16) unsigned short Bh[128 * LDSTR];
    const int t = threadIdx.x;
    const int wave = t >> 6, lane = t & 63;
    const int m0 = blockIdx.y * 128, n0 = blockIdx.x * 128;
    const int wm = (wave >> 1) * 64, wn = (wave & 1) * 64;
    const int fr = lane & 15, kq = lane >> 4;

    f32x4 acc[4][4];
    #pragma unroll
    for (int i = 0; i < 4; ++i)
        #pragma unroll
        for (int j = 0; j < 4; ++j)
            acc[i][j] = (f32x4){0.f, 0.f, 0.f, 0.f};

    const int srow = t >> 3;
    const int scol = (t & 7) * 4;

    for (int k0 = 0; k0 < K; k0 += 32) {
        #pragma unroll
        for (int p = 0; p < 4; ++p) {
            const int row = p * 32 + srow;
            const float4 av = *reinterpret_cast<const float4*>(
                A + (size_t)(m0 + row) * lda + k0 + scol);
            ushort4 a4;
            a4.x = f2b(av.x); a4.y = f2b(av.y); a4.z = f2b(av.z); a4.w = f2b(av.w);
            *reinterpret_cast<ushort4*>(&Ah[row * LDSTR + scol]) = a4;
            const float4 bv = *reinterpret_cast<const float4*>(
                B + (size_t)(n0 + row) * ldb + k0 + scol);
            ushort4 b4;
            b4.x = f2b(bv.x); b4.y = f2b(bv.y); b4.z = f2b(bv.z); b4.w = f2b(bv.w);
            *reinterpret_cast<ushort4*>(&Bh[row * LDSTR + scol]) = b4;
        }
        __syncthreads();

        bf16x8 af[4], bfr[4];
        #pragma unroll
        for (int mi = 0; mi < 4; ++mi)
            af[mi] = *reinterpret_cast<const bf16x8*>(&Ah[(wm + mi * 16 + fr) * LDSTR + kq * 8]);
        #pragma unroll
        for (int ni = 0; ni < 4; ++ni)
            bfr[ni] = *reinterpret_cast<const bf16x8*>(&Bh[(wn + ni * 16 + fr) * LDSTR + kq * 8]);
        #pragma unroll
        for (int mi = 0; mi < 4; ++mi)
            #pragma unroll
            for (int ni = 0; ni < 4; ++ni)
                acc[mi][ni] = __builtin_amdgcn_mfma_f32_16x16x32_bf16(
                    af[mi], bfr[ni], acc[mi][ni], 0, 0, 0);
        __syncthreads();
    }

    const int crow0 = m0 + wm + kq * 4;
    const int ccol0 = n0 + wn + fr;
    #pragma unroll
    for (int mi = 0; mi < 4; ++mi)
        #pragma unroll
        for (int ni = 0; ni < 4; ++ni) {
            const int col = ccol0 + ni * 16;
            #pragma unroll
            for (int i = 0; i < 4; ++i)
                C[(size_t)(crow0 + mi * 16 + i) * ldc + col] = acc[mi][ni][i];
        }
}

// ---------------------------------------------------------------------------
// Weight packing: Wkvh[672][1024] = [Wk; Wv; w1^T; a1^T; v1^T];
// w2T[1024][64], a2T[1024][64], v2T[1024][32] transposes.
// ---------------------------------------------------------------------------
__global__ __launch_bounds__(256) void pack_all(
    const float* __restrict__ Wk, const float* __restrict__ Wv,
    const float* __restrict__ w1, const float* __restrict__ a1,
    const float* __restrict__ v1, const float* __restrict__ w2,
    const float* __restrict__ a2, const float* __restrict__ v2,
    float* __restrict__ Wkvh,
    float* __restrict__ w2T, float* __restrict__ a2T, float* __restrict__ v2T)
{
    const int blk = blockIdx.x, t = threadIdx.x;
    if (blk < 512) {
        const float* s = blk < 256 ? Wk + (size_t)blk * 1024
                                   : Wv + (size_t)(blk - 256) * 1024;
        const float4 v = *reinterpret_cast<const float4*>(s + t * 4);
        *reinterpret_cast<float4*>(Wkvh + (size_t)blk * 1024 + t * 4) = v;
    } else if (blk < 672) {
        const int f = blk - 512;     // 0..159
        for (int c = t; c < 1024; c += 256) {
            float val;
            if (f < 64)       val = w1[c * 64 + f];
            else if (f < 128) val = a1[c * 64 + (f - 64)];
            else              val = v1[c * 32 + (f - 128)];
            Wkvh[(size_t)(512 + f) * 1024 + c] = val;
        }
    } else {
        const int c = blk - 672;     // 0..1023
        if (t < 64)       w2T[c * 64 + t]         = w2[t * 1024 + c];
        else if (t < 128) a2T[c * 64 + (t - 64)]  = a2[(t - 64) * 1024 + c];
        else if (t < 160) v2T[c * 32 + (t - 128)] = v2[(t - 128) * 1024 + c];
    }
}

// ---------------------------------------------------------------------------
// Slim fuse_pre: dd/aacc/vacc precomputed (GEMM) in buffers that ALIAS
// wdec/kf/vf (read idx then write idx — safe). kvh row stride 672.
// ---------------------------------------------------------------------------
__global__ __launch_bounds__(256) void fuse_pre(
    const float* __restrict__ kvh,
    const float* __restrict__ v_first, const float* __restrict__ mask,
    const float* __restrict__ w0, const float* __restrict__ a0,
    const float* __restrict__ v0,
    const float* __restrict__ k_k, const float* __restrict__ k_a,
    float* __restrict__ wdec, float* __restrict__ kf, float* __restrict__ vf,
    float* __restrict__ aab, float* __restrict__ bbb)
{
    const int n = blockIdx.x, t = threadIdx.x;
    const float m = mask[n];
    const bool live = m > 0.f;

    #pragma unroll
    for (int q = 0; q < 4; ++q) {
        const int c = q * 256 + t;
        const size_t idx = (size_t)n * 1024 + c;
        const float dd   = w0[c] + wdec[idx];   // ddl
        const float aacc = a0[c] + kf[idx];     // aal
        const float vacc = v0[c] + vf[idx];     // vvl

        const float u  = -dd;
        const float sp = fmaxf(u, 0.f) + log1pf(expf(-fabsf(u)));
        const float dec = expf(-expf(-sp - 0.6f));
        const float av = 1.f / (1.f + expf(-aacc));
        const float sv = 1.f / (1.f + expf(-vacc));

        const int  ck  = q * 64 + (c & 63);
        const float kr = kvh[(size_t)n * 672 + ck];
        const float vr = kvh[(size_t)n * 672 + 256 + ck];
        const float vfi = v_first[idx];
        const float vv  = vr + (vfi - vr) * sv;

        const float tkk = kr * k_k[c];
        float ss = tkk * tkk;
        #pragma unroll
        for (int off = 32; off > 0; off >>= 1) ss += __shfl_xor(ss, off, 64);
        const float kkv = tkk / fmaxf(sqrtf(ss), 1e-12f);

        wdec[idx] = live ? dec : 1.f;
        kf[idx]   = kr * (1.f + (av - 1.f) * k_a[c]) * m;
        vf[idx]   = vv * m;
        aab[idx]  = -kkv * m;
        bbb[idx]  = kkv * av * m;
    }
}

// ---------------------------------------------------------------------------
// WKV7 (R8 proven version): 256 blocks x 4 waves; wave = (bh, 4 value-rows).
// 16 lanes/row, float4 channels, DPP-only reduces, depth-2 register
// prefetch, XCD swizzle (4 blocks of a bh share blk%8).
// ---------------------------------------------------------------------------
__device__ __forceinline__ float qred16(float x) {
    x += __int_as_float(__builtin_amdgcn_update_dpp(
        0, __float_as_int(x), 0xB1, 0xF, 0xF, true));   // quad_perm xor1
    x += __int_as_float(__builtin_amdgcn_update_dpp(
        0, __float_as_int(x), 0x4E, 0xF, 0xF, true));   // quad_perm xor2
    x += __int_as_float(__builtin_amdgcn_update_dpp(
        0, __float_as_int(x), 0x141, 0xF, 0xF, true));  // row_half_mirror
    x += __int_as_float(__builtin_amdgcn_update_dpp(
        0, __float_as_int(x), 0x140, 0xF, 0xF, true));  // row_mirror
    return x;
}

__global__ __launch_bounds__(256, 1) void wkv7(
    const float* __restrict__ r, const float* __restrict__ wdec,
    const float* __restrict__ kf, const float* __restrict__ vf,
    const float* __restrict__ aab, const float* __restrict__ bbb,
    float* __restrict__ y)
{
    const int blk = blockIdx.x;               // 0..255
    const int m  = blk & 7;
    const int s  = blk >> 3;                  // 0..31
    const int bh = (s >> 2) * 8 + m;          // all 4 blocks of bh share m -> same XCD
    const int j  = s & 3;
    const int b = bh >> 4, h = bh & 15;
    const int wave = threadIdx.x >> 6;
    const int lane = threadIdx.x & 63;
    const int li   = lane & 15;
    const int i    = j * 16 + wave * 4 + (lane >> 4);  // value row 0..63
    const int c0   = li * 4;
    const size_t cb = (size_t)b * (1024 * 1024) + (size_t)h * 64;

    float4 S = make_float4(0.f, 0.f, 0.f, 0.f);

    float4 dA, kA, aA, bA, rA; float vA;
    float4 dB, kB, aB, bB, rB; float vB;

#define LD(T, d_, k_, a_, b_, r_, v_)                                   \
    {   const size_t p_ = cb + (size_t)(T) * 1024;                      \
        d_ = *reinterpret_cast<const float4*>(wdec + p_ + c0);          \
        k_ = *reinterpret_cast<const float4*>(kf   + p_ + c0);          \
        a_ = *reinterpret_cast<const float4*>(aab  + p_ + c0);          \
        b_ = *reinterpret_cast<const float4*>(bbb  + p_ + c0);          \
        r_ = *reinterpret_cast<const float4*>(r    + p_ + c0);          \
        v_ = vf[p_ + i]; }

#define STEP(d_, k_, a_, b_, r_, v_, YOUT)                              \
    {   float sa_ = S.x * a_.x + S.y * a_.y + S.z * a_.z + S.w * a_.w;  \
        sa_ = qred16(sa_);                                              \
        S.x = S.x * d_.x + sa_ * b_.x + v_ * k_.x;                     \
        S.y = S.y * d_.y + sa_ * b_.y + v_ * k_.y;                     \
        S.z = S.z * d_.z + sa_ * b_.z + v_ * k_.z;                     \
        S.w = S.w * d_.w + sa_ * b_.w + v_ * k_.w;                     \
        float yv_ = S.x * r_.x + S.y * r_.y + S.z * r_.z + S.w * r_.w; \
        YOUT = qred16(yv_); }

    LD(0, dA, kA, aA, bA, rA, vA);
    LD(1, dB, kB, aB, bB, rB, vB);

    for (int t = 0; t < 1024; t += 2) {
        float y0, y1;
        const int t2 = t + 2 < 1024 ? t + 2 : 1023;
        const int t3 = t + 3 < 1024 ? t + 3 : 1023;
        STEP(dA, kA, aA, bA, rA, vA, y0);
        LD(t2, dA, kA, aA, bA, rA, vA);
        STEP(dB, kB, aB, bB, rB, vB, y1);
        LD(t3, dB, kB, aB, bB, rB, vB);
        if (li == 0) {
            const size_t yb = cb + (size_t)t * 1024 + i;
            y[yb]        = y0;
            y[yb + 1024] = y1;
        }
    }
#undef LD
#undef STEP
}

// ---------------------------------------------------------------------------
// Post: groupnorm per (row, head) + rk*v residual
// ---------------------------------------------------------------------------
__global__ __launch_bounds__(256) void fuse_post(
    const float* __restrict__ y, const float* __restrict__ r,
    const float* __restrict__ kf, const float* __restrict__ vf,
    const float* __restrict__ r_k, const float* __restrict__ ln_g, const float* __restrict__ ln_b,
    float* __restrict__ yn)
{
    const int n = blockIdx.x, t = threadIdx.x;
    #pragma unroll
    for (int q = 0; q < 4; ++q) {
        const int c = q * 256 + t;
        const size_t idx = (size_t)n * 1024 + c;
        const float yv = y[idx];
        float s1 = yv, s2 = yv * yv;
        float rk = r[idx] * kf[idx] * r_k[c];
        #pragma unroll
        for (int off = 32; off > 0; off >>= 1) {
            s1 += __shfl_xor(s1, off, 64);
            s2 += __shfl_xor(s2, off, 64);
            rk += __shfl_xor(rk, off, 64);
        }
        const float mu  = s1 * (1.f / 64.f);
        const float var = s2 * (1.f / 64.f) - mu * mu;
        yn[idx] = (yv - mu) * rsqrtf(var + EPSV) * ln_g[c] + ln_b[c]
                  + rk * vf[idx];
    }
}

// ---------------------------------------------------------------------------
extern "C" void kernel_launch(void* const* d_in, const int* in_sizes, int n_in,
                              void* d_out, int out_size, void* d_ws, size_t ws_size,
                              hipStream_t stream)
{
    const float* x       = (const float*)d_in[0];
    const float* v_first = (const float*)d_in[1];
    const float* mask    = (const float*)d_in[2];
    const float* Wr      = (const float*)d_in[3];
    const float* Wk      = (const float*)d_in[4];
    const float* Wv      = (const float*)d_in[5];
    const float* Wo      = (const float*)d_in[6];
    const float* w0      = (const float*)d_in[7];
    const float* w1      = (const float*)d_in[8];
    const float* w2      = (const float*)d_in[9];
    const float* a0      = (const float*)d_in[10];
    const float* a1      = (const float*)d_in[11];
    const float* a2      = (const float*)d_in[12];
    const float* v0      = (const float*)d_in[13];
    const float* v1      = (const float*)d_in[14];
    const float* v2      = (const float*)d_in[15];
    const float* k_k     = (const float*)d_in[16];
    const float* k_a     = (const float*)d_in[17];
    const float* r_k     = (const float*)d_in[18];
    const float* ln_g    = (const float*)d_in[19];
    const float* ln_b    = (const float*)d_in[20];
    float* out = (float*)d_out;

    float* ws = (float*)d_ws;
    const size_t M4 = (size_t)NROWS * CCH;   // 4M elements
    float* rbuf = ws;
    float* wdec = ws + 1 * M4;   // pre-fuse_pre: ddl
    float* kf   = ws + 2 * M4;   // pre-fuse_pre: aal
    float* vf   = ws + 3 * M4;   // pre-fuse_pre: vvl
    float* aab  = ws + 4 * M4;   // post-wkv7: yn
    float* bbb  = ws + 5 * M4;
    float* ybuf = ws + 6 * M4;
    // region-6 temps (dead before wkv7 writes ybuf):
    float* kvh  = ybuf;                          // [4096][672]
    float* w2T  = kvh  + (size_t)NROWS * 672;    // [1024][64]
    float* a2T  = w2T  + (size_t)1024 * 64;      // [1024][64]
    float* v2T  = a2T  + (size_t)1024 * 64;      // [1024][32]
    float* Wkvh = v2T  + (size_t)1024 * 32;      // [672][1024]
    float* yn = aab;

    dim3 blk(256);
    pack_all<<<1696, blk, 0, stream>>>(Wk, Wv, w1, a1, v1, w2, a2, v2,
                                       Wkvh, w2T, a2T, v2T);
    // r: plain bf16 (no recurrence amplification)
    gemm_mfma<<<dim3(8, 32), blk, 0, stream>>>(
        x, 1024, Wr, 1024, rbuf, 1024, NROWS, 1024, 1024);
    // k,v (+hidden projections): split precision — feeds the recurrence
    gemm_split<true><<<dim3(6, 32), blk, 0, stream>>>(
        x, 1024, Wkvh, 1024, kvh, 672, NROWS, 672, 1024, 512, 576);
    // stage-2 (tiny K, tiny values): plain bf16
    gemm_mfma<<<dim3(8, 32), blk, 0, stream>>>(
        kvh + 512, 672, w2T, 64, wdec, 1024, NROWS, 1024, 64);
    gemm_mfma<<<dim3(8, 32), blk, 0, stream>>>(
        kvh + 576, 672, a2T, 64, kf, 1024, NROWS, 1024, 64);
    gemm_mfma<<<dim3(8, 32), blk, 0, stream>>>(
        kvh + 640, 672, v2T, 32, vf, 1024, NROWS, 1024, 32);
    fuse_pre<<<NROWS, blk, 0, stream>>>(kvh, v_first, mask, w0, a0, v0,
                                        k_k, k_a, wdec, kf, vf, aab, bbb);
    wkv7<<<256, blk, 0, stream>>>(rbuf, wdec, kf, vf, aab, bbb, ybuf);
    fuse_post<<<NROWS, blk, 0, stream>>>(ybuf, rbuf, kf, vf, r_k, ln_g, ln_b, yn);
    gemm_mfma<<<dim3(8, 32), blk, 0, stream>>>(
        yn, 1024, Wo, 1024, out, 1024, NROWS, 1024, 1024);
    hipMemcpyAsync(out + M4, v_first, M4 * sizeof(float),
                   hipMemcpyDeviceToDevice, stream);
}